// Round 5
// baseline (528.213 us; speedup 1.0000x reference)
//
#include <hip/hip_runtime.h>
#include <hip/hip_bf16.h>

typedef __attribute__((ext_vector_type(8))) short short8;   // 8 bf16 (4 VGPRs) — MFMA A/B frag
typedef __attribute__((ext_vector_type(4))) float f32x4;    // MFMA C/D frag

#define D_IN   256
#define D_OUT  256
#define NSAMP  32

// round-to-nearest-even f32 -> bf16
static __device__ __forceinline__ unsigned short f2bf(float f) {
    unsigned int u = __builtin_bit_cast(unsigned int, f);
    u += 0x7fffu + ((u >> 16) & 1u);
    return (unsigned short)(u >> 16);
}

static __device__ __forceinline__ void accum8(float* a, uint4 v) {
    a[0] += __builtin_bit_cast(float, v.x << 16);
    a[1] += __builtin_bit_cast(float, v.x & 0xffff0000u);
    a[2] += __builtin_bit_cast(float, v.y << 16);
    a[3] += __builtin_bit_cast(float, v.y & 0xffff0000u);
    a[4] += __builtin_bit_cast(float, v.z << 16);
    a[5] += __builtin_bit_cast(float, v.z & 0xffff0000u);
    a[6] += __builtin_bit_cast(float, v.w << 16);
    a[7] += __builtin_bit_cast(float, v.w & 0xffff0000u);
}

// Convert W [256][256] f32 row-major -> bf16 in MFMA B-fragment order.
__global__ void wconv_kernel(const float* __restrict__ W,
                             unsigned short* __restrict__ wsw) {
    const int k = blockIdx.x;    // 0..255
    const int n = threadIdx.x;   // 0..255
    const float v = W[k * D_OUT + n];
    const int ks = k >> 5, kg = (k >> 3) & 3, j = k & 7;
    const int nf = n >> 4, c = n & 15;
    const int lane = kg * 16 + c;
    const int dst = ((ks * 16 + nf) * 64 + lane) * 8 + j;
    wsw[dst] = f2bf(v);
}

// ---------------------------------------------------------------------------
// Kernel 1: Y = features @ W  (bf16 output).  M-tile = 64 rows per block.
// ---------------------------------------------------------------------------
__global__ __launch_bounds__(256, 4) void ygemm_kernel(
        const float* __restrict__ feat,
        const unsigned short* __restrict__ wsw,
        unsigned short* __restrict__ Y,
        int n_table)
{
    __shared__ __attribute__((aligned(16))) unsigned char lds[64 * 512]; // 64 rows x 256 bf16 (swizzled)

    const int tid  = threadIdx.x;
    const int wv   = tid >> 6;
    const int lane = tid & 63;
    const int row0 = blockIdx.x * 64;

    // stage A tile: f32 -> bf16 -> LDS.  4 threads per row, 16 float4s each.
    const int r = tid >> 2;        // 0..63
    const int q = tid & 3;
    #pragma unroll 4
    for (int it = 0; it < 16; ++it) {
        const int cidx = it * 4 + q;            // float4 index 0..63
        const int grow = row0 + r;
        float4 f = make_float4(0.f, 0.f, 0.f, 0.f);
        if (grow < n_table)
            f = *(const float4*)(feat + (size_t)grow * D_IN + cidx * 4);
        ushort4 pk;
        pk.x = f2bf(f.x); pk.y = f2bf(f.y); pk.z = f2bf(f.z); pk.w = f2bf(f.w);
        unsigned int bo = (unsigned int)(r * 512 + cidx * 8) ^ ((unsigned int)(r & 7) << 4);
        *(ushort4*)(&lds[bo]) = pk;
    }
    __syncthreads();

    // MFMA: A from LDS, B frags from wsw (L2-hot)
    f32x4 acc[16];
    #pragma unroll
    for (int i = 0; i < 16; ++i) acc[i] = (f32x4)(0.0f);

    const int arow = wv * 16 + (lane & 15);
    const int acol = (lane >> 4) * 16;
    const short8* __restrict__ wp = (const short8*)wsw;

    #pragma unroll
    for (int ks = 0; ks < 8; ++ks) {
        unsigned int bo = (unsigned int)(arow * 512 + ks * 64 + acol)
                        ^ ((unsigned int)(arow & 7) << 4);
        const short8 afrag = *(const short8*)(&lds[bo]);
        #pragma unroll
        for (int nf = 0; nf < 16; ++nf) {
            const short8 bfrag = wp[(ks * 16 + nf) * 64 + lane];
            acc[nf] = __builtin_amdgcn_mfma_f32_16x16x32_bf16(afrag, bfrag, acc[nf], 0, 0, 0);
        }
    }

    // store Y (bf16).  D frag: row = wv*16 + 4*(lane>>4) + j, col = nf*16 + (lane&15)
    const int rbase = row0 + wv * 16 + (lane >> 4) * 4;
    const int c0 = lane & 15;
    #pragma unroll
    for (int j = 0; j < 4; ++j) {
        const int rg = rbase + j;
        if (rg < n_table) {
            #pragma unroll
            for (int nf = 0; nf < 16; ++nf)
                Y[(size_t)rg * D_OUT + nf * 16 + c0] = f2bf(acc[nf][j]);
        }
    }
}

// ---------------------------------------------------------------------------
// Kernel 2: out = l2norm(relu(mean_{33}(Y[gather]) + b)).  One half-wave per
// node; lane (l&31) owns 8 contiguous channels (16 B bf16 per row load).
// ---------------------------------------------------------------------------
__global__ __launch_bounds__(256) void gather_kernel(
        const int*  __restrict__ node_idx,
        const int*  __restrict__ neigh_idx,
        const unsigned short* __restrict__ Y,
        const float* __restrict__ bias,
        float* __restrict__ out,
        int n_nodes)
{
    const int tid  = threadIdx.x;
    const int l    = tid & 31;
    const int node = blockIdx.x * 8 + (tid >> 5);
    const bool valid = node < n_nodes;

    const int nb   = valid ? neigh_idx[node * NSAMP + l] : 0;
    const int sidx = valid ? node_idx[node] : 0;

    float a[8] = {0.f, 0.f, 0.f, 0.f, 0.f, 0.f, 0.f, 0.f};

    #pragma unroll 8
    for (int s = 0; s < NSAMP; ++s) {
        const int idx = __shfl(nb, s, 32);
        const uint4 v = *(const uint4*)(Y + (size_t)idx * D_OUT + l * 8);
        accum8(a, v);
    }
    {   // self row
        const uint4 v = *(const uint4*)(Y + (size_t)sidx * D_OUT + l * 8);
        accum8(a, v);
    }

    const float sc = 1.0f / (float)(NSAMP + 1);
    const float4 b0 = *(const float4*)(bias + l * 8);
    const float4 b1 = *(const float4*)(bias + l * 8 + 4);
    float o[8];
    o[0] = fmaxf(a[0] * sc + b0.x, 0.f);
    o[1] = fmaxf(a[1] * sc + b0.y, 0.f);
    o[2] = fmaxf(a[2] * sc + b0.z, 0.f);
    o[3] = fmaxf(a[3] * sc + b0.w, 0.f);
    o[4] = fmaxf(a[4] * sc + b1.x, 0.f);
    o[5] = fmaxf(a[5] * sc + b1.y, 0.f);
    o[6] = fmaxf(a[6] * sc + b1.z, 0.f);
    o[7] = fmaxf(a[7] * sc + b1.w, 0.f);

    float p = 0.f;
    #pragma unroll
    for (int j = 0; j < 8; ++j) p += o[j] * o[j];
    #pragma unroll
    for (int m = 1; m < 32; m <<= 1) p += __shfl_xor(p, m, 64); // stays within 32-lane segment
    const float inv = 1.0f / fmaxf(sqrtf(p), 1e-12f);

    if (valid) {
        float4 s0, s1;
        s0.x = o[0] * inv; s0.y = o[1] * inv; s0.z = o[2] * inv; s0.w = o[3] * inv;
        s1.x = o[4] * inv; s1.y = o[5] * inv; s1.z = o[6] * inv; s1.w = o[7] * inv;
        float* op = out + (size_t)node * D_OUT + l * 8;
        *(float4*)op       = s0;
        *(float4*)(op + 4) = s1;
    }
}

// ---------------------------------------------------------------------------
// Fallback (round-1 fused kernel) if ws can't hold Y
// ---------------------------------------------------------------------------
__global__ __launch_bounds__(256, 4) void gcn_fused_kernel(
        const int*  __restrict__ node_idx,
        const int*  __restrict__ neigh_idx,
        const float* __restrict__ features,
        const unsigned short* __restrict__ wsw,
        const float* __restrict__ bias,
        float* __restrict__ out,
        int n_nodes)
{
    __shared__ __attribute__((aligned(16))) unsigned char lds[64 * D_IN * 2];

    const int tid  = threadIdx.x;
    const int wv   = tid >> 6;
    const int lane = tid & 63;
    const int block_m0 = blockIdx.x * 64;

    const float scale = 1.0f / (float)(NSAMP + 1);
    for (int r = 0; r < 16; ++r) {
        const int row  = wv * 16 + r;
        const int node = block_m0 + row;
        float ax = 0.f, ay = 0.f, az = 0.f, aw = 0.f;
        if (node < n_nodes) {
            const int nb   = neigh_idx[node * NSAMP + (lane & 31)];
            const int self = node_idx[node];
            {
                const float4 v = *(const float4*)(features + (size_t)self * D_IN + lane * 4);
                ax += v.x; ay += v.y; az += v.z; aw += v.w;
            }
            #pragma unroll 8
            for (int s = 0; s < NSAMP; ++s) {
                const int idx = __shfl(nb, s, 64);
                const float4 v = *(const float4*)(features + (size_t)idx * D_IN + lane * 4);
                ax += v.x; ay += v.y; az += v.z; aw += v.w;
            }
            ax *= scale; ay *= scale; az *= scale; aw *= scale;
        }
        ushort4 pk;
        pk.x = f2bf(ax); pk.y = f2bf(ay); pk.z = f2bf(az); pk.w = f2bf(aw);
        unsigned int bo = (unsigned int)(row * 512 + lane * 8) ^ ((unsigned int)(row & 7) << 4);
        *(ushort4*)(&lds[bo]) = pk;
    }
    __syncthreads();

    f32x4 acc[16];
    #pragma unroll
    for (int i = 0; i < 16; ++i) acc[i] = (f32x4)(0.0f);

    const int arow = wv * 16 + (lane & 15);
    const int acol = (lane >> 4) * 16;
    const short8* __restrict__ wp = (const short8*)wsw;

    #pragma unroll
    for (int ks = 0; ks < 8; ++ks) {
        unsigned int bo = (unsigned int)(arow * 512 + ks * 64 + acol)
                        ^ ((unsigned int)(arow & 7) << 4);
        const short8 afrag = *(const short8*)(&lds[bo]);
        #pragma unroll
        for (int nf = 0; nf < 16; ++nf) {
            const short8 bfrag = wp[(ks * 16 + nf) * 64 + lane];
            acc[nf] = __builtin_amdgcn_mfma_f32_16x16x32_bf16(afrag, bfrag, acc[nf], 0, 0, 0);
        }
    }

    float p[4] = {0.f, 0.f, 0.f, 0.f};
    #pragma unroll
    for (int nf = 0; nf < 16; ++nf) {
        const float bv = bias[nf * 16 + (lane & 15)];
        #pragma unroll
        for (int j = 0; j < 4; ++j) {
            float v = acc[nf][j] + bv;
            v = fmaxf(v, 0.0f);
            acc[nf][j] = v;
            p[j] += v * v;
        }
    }
    #pragma unroll
    for (int m = 1; m < 16; m <<= 1) {
        p[0] += __shfl_xor(p[0], m, 64);
        p[1] += __shfl_xor(p[1], m, 64);
        p[2] += __shfl_xor(p[2], m, 64);
        p[3] += __shfl_xor(p[3], m, 64);
    }
    float inv[4];
    #pragma unroll
    for (int j = 0; j < 4; ++j)
        inv[j] = 1.0f / fmaxf(sqrtf(p[j]), 1e-12f);

    const int rbase = block_m0 + wv * 16 + (lane >> 4) * 4;
    const int c0 = lane & 15;
    #pragma unroll
    for (int j = 0; j < 4; ++j) {
        const int rg = rbase + j;
        if (rg < n_nodes) {
            #pragma unroll
            for (int nf = 0; nf < 16; ++nf)
                out[(size_t)rg * D_OUT + nf * 16 + c0] = acc[nf][j] * inv[j];
        }
    }
}

extern "C" void kernel_launch(void* const* d_in, const int* in_sizes, int n_in,
                              void* d_out, int out_size, void* d_ws, size_t ws_size,
                              hipStream_t stream) {
    const int*   node_idx  = (const int*)d_in[0];
    const int*   neigh_idx = (const int*)d_in[1];
    const float* features  = (const float*)d_in[2];
    const float* W         = (const float*)d_in[3];
    const float* bias      = (const float*)d_in[4];
    float*       out       = (float*)d_out;
    const int n_nodes = in_sizes[0];
    const int n_table = in_sizes[2] / D_IN;

    unsigned short* wsw = (unsigned short*)d_ws;                      // 128 KB W frags
    unsigned short* Y   = (unsigned short*)((char*)d_ws + 131072);    // n_table x 256 bf16

    const size_t need = 131072 + (size_t)n_table * D_OUT * 2;

    hipLaunchKernelGGL(wconv_kernel, dim3(D_IN), dim3(D_OUT), 0, stream, W, wsw);

    if (ws_size >= need) {
        const int yblocks = (n_table + 63) / 64;
        hipLaunchKernelGGL(ygemm_kernel, dim3(yblocks), dim3(256), 0, stream,
                           features, wsw, Y, n_table);
        const int gblocks = (n_nodes + 7) / 8;
        hipLaunchKernelGGL(gather_kernel, dim3(gblocks), dim3(256), 0, stream,
                           node_idx, neigh_idx, Y, bias, out, n_nodes);
    } else {
        const int nblocks = (n_nodes + 63) / 64;
        hipLaunchKernelGGL(gcn_fused_kernel, dim3(nblocks), dim3(256), 0, stream,
                           node_idx, neigh_idx, features, wsw, bias, out, n_nodes);
    }
}

// Round 6
// 514.884 us; speedup vs baseline: 1.0259x; 1.0259x over previous
//
#include <hip/hip_runtime.h>
#include <hip/hip_bf16.h>

typedef __attribute__((ext_vector_type(8))) short short8;   // 8 bf16 (4 VGPRs) — MFMA A/B frag
typedef __attribute__((ext_vector_type(4))) float f32x4;    // MFMA C/D frag

#define D_IN   256
#define D_OUT  256
#define NSAMP  32

// round-to-nearest-even f32 -> bf16
static __device__ __forceinline__ unsigned short f2bf(float f) {
    unsigned int u = __builtin_bit_cast(unsigned int, f);
    u += 0x7fffu + ((u >> 16) & 1u);
    return (unsigned short)(u >> 16);
}

static __device__ __forceinline__ void accum8(float* a, uint4 v) {
    a[0] += __builtin_bit_cast(float, v.x << 16);
    a[1] += __builtin_bit_cast(float, v.x & 0xffff0000u);
    a[2] += __builtin_bit_cast(float, v.y << 16);
    a[3] += __builtin_bit_cast(float, v.y & 0xffff0000u);
    a[4] += __builtin_bit_cast(float, v.z << 16);
    a[5] += __builtin_bit_cast(float, v.z & 0xffff0000u);
    a[6] += __builtin_bit_cast(float, v.w << 16);
    a[7] += __builtin_bit_cast(float, v.w & 0xffff0000u);
}

// Convert W [256][256] f32 row-major -> bf16 in MFMA B-fragment order.
// For k-step ks (32 k's) and n-frag nf (16 cols), lane l holds
// B[k = ks*32 + 8*(l>>4) + j][n = nf*16 + (l&15)], j=0..7, as 16 contiguous bytes.
__global__ void wconv_kernel(const float* __restrict__ W,
                             unsigned short* __restrict__ wsw) {
    const int k = blockIdx.x;    // 0..255
    const int n = threadIdx.x;   // 0..255
    const float v = W[k * D_OUT + n];
    const int ks = k >> 5, kg = (k >> 3) & 3, j = k & 7;
    const int nf = n >> 4, c = n & 15;
    const int lane = kg * 16 + c;
    const int dst = ((ks * 16 + nf) * 64 + lane) * 8 + j;
    wsw[dst] = f2bf(v);
}

// ---------------------------------------------------------------------------
// Kernel 1: Y = features @ W  (bf16 output).  M-tile = 128 rows per block.
// 4 waves; wave w owns rows [w*32, w*32+32) as two 16-row strips sharing each
// B-fragment (acc[2][16]).  __launch_bounds__(256,2) -> 256-reg budget so the
// 16 B-frag loads per k-step stay in flight (round-5 fix: (256,4) capped regs
// at 128 and serialized every MFMA behind an L2 load; MfmaUtil was 5.4%).
// ---------------------------------------------------------------------------
__global__ __launch_bounds__(256, 2) void ygemm_kernel(
        const float* __restrict__ feat,
        const unsigned short* __restrict__ wsw,
        unsigned short* __restrict__ Y,
        int n_table)
{
    __shared__ __attribute__((aligned(16))) unsigned char lds[128 * 512]; // 128 rows x 256 bf16 (swizzled)

    const int tid  = threadIdx.x;
    const int wv   = tid >> 6;
    const int lane = tid & 63;
    const int row0 = blockIdx.x * 128;

    // stage A tile: f32 -> bf16 -> LDS.  One float4 per thread per iteration,
    // fully coalesced (consecutive tid -> consecutive 16B within a row).
    #pragma unroll 8
    for (int it = 0; it < 32; ++it) {
        const int idx = it * 256 + tid;     // 0..8191
        const int r   = idx >> 6;           // row 0..127
        const int c4  = idx & 63;           // float4 index within row
        const int grow = row0 + r;
        float4 f = make_float4(0.f, 0.f, 0.f, 0.f);
        if (grow < n_table)
            f = *(const float4*)(feat + (size_t)grow * D_IN + c4 * 4);
        ushort4 pk;
        pk.x = f2bf(f.x); pk.y = f2bf(f.y); pk.z = f2bf(f.z); pk.w = f2bf(f.w);
        unsigned int bo = (unsigned int)(r * 512 + c4 * 8) ^ ((unsigned int)(r & 7) << 4);
        *(ushort4*)(&lds[bo]) = pk;
    }
    __syncthreads();

    // MFMA: A frags from LDS, B frags from wsw (L2-resident 128 KB)
    f32x4 acc[2][16];
    #pragma unroll
    for (int s = 0; s < 2; ++s)
        #pragma unroll
        for (int i = 0; i < 16; ++i) acc[s][i] = (f32x4)(0.0f);

    const int arow0 = wv * 32 + (lane & 15);      // strip 0 row within tile
    const int acol  = (lane >> 4) * 16;           // byte offset of this lane's 8 bf16
    const short8* __restrict__ wp = (const short8*)wsw;

    #pragma unroll
    for (int ks = 0; ks < 8; ++ks) {
        unsigned int bo0 = (unsigned int)(arow0 * 512 + ks * 64 + acol)
                         ^ ((unsigned int)(arow0 & 7) << 4);
        unsigned int bo1 = (unsigned int)((arow0 + 16) * 512 + ks * 64 + acol)
                         ^ ((unsigned int)((arow0 + 16) & 7) << 4);
        const short8 af0 = *(const short8*)(&lds[bo0]);
        const short8 af1 = *(const short8*)(&lds[bo1]);
        #pragma unroll
        for (int nf = 0; nf < 16; ++nf) {
            const short8 bfrag = wp[(ks * 16 + nf) * 64 + lane];
            acc[0][nf] = __builtin_amdgcn_mfma_f32_16x16x32_bf16(af0, bfrag, acc[0][nf], 0, 0, 0);
            acc[1][nf] = __builtin_amdgcn_mfma_f32_16x16x32_bf16(af1, bfrag, acc[1][nf], 0, 0, 0);
        }
    }

    // store Y (bf16).  D frag: row = 4*(lane>>4) + j, col = nf*16 + (lane&15)
    const int c0 = lane & 15;
    #pragma unroll
    for (int s = 0; s < 2; ++s) {
        const int rbase = row0 + wv * 32 + s * 16 + (lane >> 4) * 4;
        #pragma unroll
        for (int j = 0; j < 4; ++j) {
            const int rg = rbase + j;
            if (rg < n_table) {
                #pragma unroll
                for (int nf = 0; nf < 16; ++nf)
                    Y[(size_t)rg * D_OUT + nf * 16 + c0] = f2bf(acc[s][nf][j]);
            }
        }
    }
}

// ---------------------------------------------------------------------------
// Kernel 2: out = l2norm(relu(mean_{33}(Y[gather]) + b)).  One half-wave per
// node; lane (l&31) owns 8 contiguous channels (16 B bf16 per row load).
// ---------------------------------------------------------------------------
__global__ __launch_bounds__(256) void gather_kernel(
        const int*  __restrict__ node_idx,
        const int*  __restrict__ neigh_idx,
        const unsigned short* __restrict__ Y,
        const float* __restrict__ bias,
        float* __restrict__ out,
        int n_nodes)
{
    const int tid  = threadIdx.x;
    const int l    = tid & 31;
    const int node = blockIdx.x * 8 + (tid >> 5);
    const bool valid = node < n_nodes;

    const int nb   = valid ? neigh_idx[node * NSAMP + l] : 0;
    const int sidx = valid ? node_idx[node] : 0;

    float a[8] = {0.f, 0.f, 0.f, 0.f, 0.f, 0.f, 0.f, 0.f};

    #pragma unroll 8
    for (int s = 0; s < NSAMP; ++s) {
        const int idx = __shfl(nb, s, 32);
        const uint4 v = *(const uint4*)(Y + (size_t)idx * D_OUT + l * 8);
        accum8(a, v);
    }
    {   // self row
        const uint4 v = *(const uint4*)(Y + (size_t)sidx * D_OUT + l * 8);
        accum8(a, v);
    }

    const float sc = 1.0f / (float)(NSAMP + 1);
    const float4 b0 = *(const float4*)(bias + l * 8);
    const float4 b1 = *(const float4*)(bias + l * 8 + 4);
    float o[8];
    o[0] = fmaxf(a[0] * sc + b0.x, 0.f);
    o[1] = fmaxf(a[1] * sc + b0.y, 0.f);
    o[2] = fmaxf(a[2] * sc + b0.z, 0.f);
    o[3] = fmaxf(a[3] * sc + b0.w, 0.f);
    o[4] = fmaxf(a[4] * sc + b1.x, 0.f);
    o[5] = fmaxf(a[5] * sc + b1.y, 0.f);
    o[6] = fmaxf(a[6] * sc + b1.z, 0.f);
    o[7] = fmaxf(a[7] * sc + b1.w, 0.f);

    float p = 0.f;
    #pragma unroll
    for (int j = 0; j < 8; ++j) p += o[j] * o[j];
    #pragma unroll
    for (int m = 1; m < 32; m <<= 1) p += __shfl_xor(p, m, 64); // stays within 32-lane segment
    const float inv = 1.0f / fmaxf(sqrtf(p), 1e-12f);

    if (valid) {
        float4 s0, s1;
        s0.x = o[0] * inv; s0.y = o[1] * inv; s0.z = o[2] * inv; s0.w = o[3] * inv;
        s1.x = o[4] * inv; s1.y = o[5] * inv; s1.z = o[6] * inv; s1.w = o[7] * inv;
        float* op = out + (size_t)node * D_OUT + l * 8;
        *(float4*)op       = s0;
        *(float4*)(op + 4) = s1;
    }
}

// ---------------------------------------------------------------------------
// Fallback (round-1 fused kernel) if ws can't hold Y
// ---------------------------------------------------------------------------
__global__ __launch_bounds__(256, 4) void gcn_fused_kernel(
        const int*  __restrict__ node_idx,
        const int*  __restrict__ neigh_idx,
        const float* __restrict__ features,
        const unsigned short* __restrict__ wsw,
        const float* __restrict__ bias,
        float* __restrict__ out,
        int n_nodes)
{
    __shared__ __attribute__((aligned(16))) unsigned char lds[64 * D_IN * 2];

    const int tid  = threadIdx.x;
    const int wv   = tid >> 6;
    const int lane = tid & 63;
    const int block_m0 = blockIdx.x * 64;

    const float scale = 1.0f / (float)(NSAMP + 1);
    for (int r = 0; r < 16; ++r) {
        const int row  = wv * 16 + r;
        const int node = block_m0 + row;
        float ax = 0.f, ay = 0.f, az = 0.f, aw = 0.f;
        if (node < n_nodes) {
            const int nb   = neigh_idx[node * NSAMP + (lane & 31)];
            const int self = node_idx[node];
            {
                const float4 v = *(const float4*)(features + (size_t)self * D_IN + lane * 4);
                ax += v.x; ay += v.y; az += v.z; aw += v.w;
            }
            #pragma unroll 8
            for (int s = 0; s < NSAMP; ++s) {
                const int idx = __shfl(nb, s, 64);
                const float4 v = *(const float4*)(features + (size_t)idx * D_IN + lane * 4);
                ax += v.x; ay += v.y; az += v.z; aw += v.w;
            }
            ax *= scale; ay *= scale; az *= scale; aw *= scale;
        }
        ushort4 pk;
        pk.x = f2bf(ax); pk.y = f2bf(ay); pk.z = f2bf(az); pk.w = f2bf(aw);
        unsigned int bo = (unsigned int)(row * 512 + lane * 8) ^ ((unsigned int)(row & 7) << 4);
        *(ushort4*)(&lds[bo]) = pk;
    }
    __syncthreads();

    f32x4 acc[16];
    #pragma unroll
    for (int i = 0; i < 16; ++i) acc[i] = (f32x4)(0.0f);

    const int arow = wv * 16 + (lane & 15);
    const int acol = (lane >> 4) * 16;
    const short8* __restrict__ wp = (const short8*)wsw;

    #pragma unroll
    for (int ks = 0; ks < 8; ++ks) {
        unsigned int bo = (unsigned int)(arow * 512 + ks * 64 + acol)
                        ^ ((unsigned int)(arow & 7) << 4);
        const short8 afrag = *(const short8*)(&lds[bo]);
        #pragma unroll
        for (int nf = 0; nf < 16; ++nf) {
            const short8 bfrag = wp[(ks * 16 + nf) * 64 + lane];
            acc[nf] = __builtin_amdgcn_mfma_f32_16x16x32_bf16(afrag, bfrag, acc[nf], 0, 0, 0);
        }
    }

    float p[4] = {0.f, 0.f, 0.f, 0.f};
    #pragma unroll
    for (int nf = 0; nf < 16; ++nf) {
        const float bv = bias[nf * 16 + (lane & 15)];
        #pragma unroll
        for (int j = 0; j < 4; ++j) {
            float v = acc[nf][j] + bv;
            v = fmaxf(v, 0.0f);
            acc[nf][j] = v;
            p[j] += v * v;
        }
    }
    #pragma unroll
    for (int m = 1; m < 16; m <<= 1) {
        p[0] += __shfl_xor(p[0], m, 64);
        p[1] += __shfl_xor(p[1], m, 64);
        p[2] += __shfl_xor(p[2], m, 64);
        p[3] += __shfl_xor(p[3], m, 64);
    }
    float inv[4];
    #pragma unroll
    for (int j = 0; j < 4; ++j)
        inv[j] = 1.0f / fmaxf(sqrtf(p[j]), 1e-12f);

    const int rbase = block_m0 + wv * 16 + (lane >> 4) * 4;
    const int c0 = lane & 15;
    #pragma unroll
    for (int j = 0; j < 4; ++j) {
        const int rg = rbase + j;
        if (rg < n_nodes) {
            #pragma unroll
            for (int nf = 0; nf < 16; ++nf)
                out[(size_t)rg * D_OUT + nf * 16 + c0] = acc[nf][j] * inv[j];
        }
    }
}

extern "C" void kernel_launch(void* const* d_in, const int* in_sizes, int n_in,
                              void* d_out, int out_size, void* d_ws, size_t ws_size,
                              hipStream_t stream) {
    const int*   node_idx  = (const int*)d_in[0];
    const int*   neigh_idx = (const int*)d_in[1];
    const float* features  = (const float*)d_in[2];
    const float* W         = (const float*)d_in[3];
    const float* bias      = (const float*)d_in[4];
    float*       out       = (float*)d_out;
    const int n_nodes = in_sizes[0];
    const int n_table = in_sizes[2] / D_IN;

    unsigned short* wsw = (unsigned short*)d_ws;                      // 128 KB W frags
    unsigned short* Y   = (unsigned short*)((char*)d_ws + 131072);    // n_table x 256 bf16

    const size_t need = 131072 + (size_t)n_table * D_OUT * 2;

    hipLaunchKernelGGL(wconv_kernel, dim3(D_IN), dim3(D_OUT), 0, stream, W, wsw);

    if (ws_size >= need) {
        const int yblocks = (n_table + 127) / 128;
        hipLaunchKernelGGL(ygemm_kernel, dim3(yblocks), dim3(256), 0, stream,
                           features, wsw, Y, n_table);
        const int gblocks = (n_nodes + 7) / 8;
        hipLaunchKernelGGL(gather_kernel, dim3(gblocks), dim3(256), 0, stream,
                           node_idx, neigh_idx, Y, bias, out, n_nodes);
    } else {
        const int nblocks = (n_nodes + 63) / 64;
        hipLaunchKernelGGL(gcn_fused_kernel, dim3(nblocks), dim3(256), 0, stream,
                           node_idx, neigh_idx, features, wsw, bias, out, n_nodes);
    }
}